// Round 6
// baseline (244.885 us; speedup 1.0000x reference)
//
#include <hip/hip_runtime.h>

// SparseActivation: per row of D=2048 fp32, keep top K=204 by |x|, scale by D/K.
// TWO rows per WAVE, 32 abs-values/lane per row. Two independent bitwise
// binary searches run interleaved in one loop: row B's compare throughput
// fills row A's reduce/readlane/branch latency bubbles (and vice versa) --
// attacks the serial-chain stall that bounded rounds 2-5 without relying on
// occupancy. Early exit when count(>=test)==K (set is exactly the top-K);
// exact lowest-index-first tie-break fallback.

constexpr int D_DIM = 2048;
constexpr int K_SEL = 204;     // int(2048 * 0.1)
constexpr int NT    = 256;     // 4 waves/block, 2 rows/wave -> 8 rows/block
constexpr int EPL   = 32;      // elements per lane per row

// Full-wave64 integer sum via DPP; returns total (scalar, from lane 63).
__device__ __forceinline__ int dpp_reduce_add(int x) {
    x += __builtin_amdgcn_update_dpp(0, x, 0x111, 0xF, 0xF, true);  // row_shr:1
    x += __builtin_amdgcn_update_dpp(0, x, 0x112, 0xF, 0xF, true);  // row_shr:2
    x += __builtin_amdgcn_update_dpp(0, x, 0x114, 0xF, 0xF, true);  // row_shr:4
    x += __builtin_amdgcn_update_dpp(0, x, 0x118, 0xF, 0xF, true);  // row_shr:8
    x += __builtin_amdgcn_update_dpp(0, x, 0x142, 0xA, 0xF, false); // row_bcast:15
    x += __builtin_amdgcn_update_dpp(0, x, 0x143, 0xC, 0xF, false); // row_bcast:31
    return __builtin_amdgcn_readlane(x, 63);
}

// Apply threshold + store one row. done => thr is exact (no ties to resolve);
// otherwise T is the exact K-th largest and boundary ties are ranked exactly.
__device__ __forceinline__ void finish_row(const unsigned (&a)[EPL], unsigned signs,
                                           bool done, unsigned thr, unsigned T,
                                           float* __restrict__ outr, int lane) {
    const float scale = 2048.0f / 204.0f;
    float4* op = reinterpret_cast<float4*>(outr);

    if (!done) {
        // Boundary bookkeeping (gt in low 16 bits, eq in high 16 bits).
        int ge_pack = 0;
#pragma unroll
        for (int j = 0; j < EPL; ++j) {
            ge_pack += (a[j] > T) ? 1 : 0;
            ge_pack += (a[j] == T) ? (1 << 16) : 0;
        }
        const int tot = dpp_reduce_add(ge_pack);
        const int cnt_gt = tot & 0xFFFF;
        const int neq = tot >> 16;
        const int r = K_SEL - cnt_gt;   // equals to keep

        if (neq != r) {
            // Rare: among ==T keep the r with lowest global index.
            const unsigned long long lt =
                (lane == 0) ? 0ull : (~0ull >> (64 - lane));
            int base = 0;
            for (int b = 0; b < 8; ++b) {
                unsigned long long m[4];
#pragma unroll
                for (int e = 0; e < 4; ++e) m[e] = __ballot(a[4 * b + e] == T);
                int cm = 0;
#pragma unroll
                for (int e = 0; e < 4; ++e) cm += __popcll(m[e] & lt);
                int partial = 0;
                float v[4];
#pragma unroll
                for (int e = 0; e < 4; ++e) {
                    const int j = 4 * b + e;
                    const int rank = base + cm + partial;
                    const bool eq = (a[j] == T);
                    const bool sel = (a[j] > T) || (eq && rank < r);
                    const float val =
                        __uint_as_float(a[j] | (((signs >> j) & 1u) << 31)) * scale;
                    v[e] = sel ? val : 0.0f;
                    partial += (int)((m[e] >> lane) & 1ull);
                }
                op[b * 64 + lane] = make_float4(v[0], v[1], v[2], v[3]);
#pragma unroll
                for (int e = 0; e < 4; ++e) base += __popcll(m[e]);
            }
            return;
        }
        thr = T;  // neq == r: keep everything >= T, no tie handling needed
    }

    // Common path: keep everything >= thr; compute+store per 16B chunk.
#pragma unroll
    for (int b = 0; b < 8; ++b) {
        float v[4];
#pragma unroll
        for (int e = 0; e < 4; ++e) {
            const int j = 4 * b + e;
            const float val =
                __uint_as_float(a[j] | (((signs >> j) & 1u) << 31)) * scale;
            v[e] = (a[j] >= thr) ? val : 0.0f;
        }
        op[b * 64 + lane] = make_float4(v[0], v[1], v[2], v[3]);
    }
}

__global__ __launch_bounds__(NT) void sparse_topk_kernel(const float* __restrict__ x,
                                                         float* __restrict__ out) {
    const int wave = threadIdx.x >> 6;
    const int lane = threadIdx.x & 63;
    const long long rowA = (long long)blockIdx.x * 8 + wave * 2;
    const float* xA = x + rowA * D_DIM;
    float* oA = out + rowA * D_DIM;

    // Element (b, lane, e): row index = 256*b + 4*lane + e, j = 4*b + e.
    unsigned A[EPL], B[EPL];
    unsigned sA = 0u, sB = 0u;
    const float4* pA = reinterpret_cast<const float4*>(xA);
    const float4* pB = reinterpret_cast<const float4*>(xA + D_DIM);
#pragma unroll
    for (int b = 0; b < 8; ++b) {
        const float4 f = pA[b * 64 + lane];
        const unsigned w0 = __float_as_uint(f.x), w1 = __float_as_uint(f.y);
        const unsigned w2 = __float_as_uint(f.z), w3 = __float_as_uint(f.w);
        A[4 * b + 0] = w0 & 0x7fffffffu; sA |= (w0 >> 31) << (4 * b + 0);
        A[4 * b + 1] = w1 & 0x7fffffffu; sA |= (w1 >> 31) << (4 * b + 1);
        A[4 * b + 2] = w2 & 0x7fffffffu; sA |= (w2 >> 31) << (4 * b + 2);
        A[4 * b + 3] = w3 & 0x7fffffffu; sA |= (w3 >> 31) << (4 * b + 3);
    }
#pragma unroll
    for (int b = 0; b < 8; ++b) {
        const float4 f = pB[b * 64 + lane];
        const unsigned w0 = __float_as_uint(f.x), w1 = __float_as_uint(f.y);
        const unsigned w2 = __float_as_uint(f.z), w3 = __float_as_uint(f.w);
        B[4 * b + 0] = w0 & 0x7fffffffu; sB |= (w0 >> 31) << (4 * b + 0);
        B[4 * b + 1] = w1 & 0x7fffffffu; sB |= (w1 >> 31) << (4 * b + 1);
        B[4 * b + 2] = w2 & 0x7fffffffu; sB |= (w2 >> 31) << (4 * b + 2);
        B[4 * b + 3] = w3 & 0x7fffffffu; sB |= (w3 >> 31) << (4 * b + 3);
    }

    // Interleaved dual bitwise descent. Decisions are scalar + predicated so
    // the two compare/reduce dataflows stay branch-free and overlap.
    unsigned TA = 0u, TB = 0u, thrA = 0u, thrB = 0u;
    bool doneA = false, doneB = false;
#pragma unroll 1
    for (int bit = 30; bit >= 0; --bit) {
        const unsigned tA = TA | (1u << bit);
        const unsigned tB = TB | (1u << bit);
        int c0 = 0, c1 = 0, c2 = 0, c3 = 0;
        int d0 = 0, d1 = 0, d2 = 0, d3 = 0;
#pragma unroll
        for (int j = 0; j < EPL; j += 4) {
            c0 += (A[j + 0] >= tA) ? 1 : 0;
            c1 += (A[j + 1] >= tA) ? 1 : 0;
            c2 += (A[j + 2] >= tA) ? 1 : 0;
            c3 += (A[j + 3] >= tA) ? 1 : 0;
            d0 += (B[j + 0] >= tB) ? 1 : 0;
            d1 += (B[j + 1] >= tB) ? 1 : 0;
            d2 += (B[j + 2] >= tB) ? 1 : 0;
            d3 += (B[j + 3] >= tB) ? 1 : 0;
        }
        const int cntA = dpp_reduce_add((c0 + c1) + (c2 + c3));
        const int cntB = dpp_reduce_add((d0 + d1) + (d2 + d3));
        if (!doneA) {
            if (cntA == K_SEL)     { thrA = tA; doneA = true; }
            else if (cntA > K_SEL) { TA = tA; }
        }
        if (!doneB) {
            if (cntB == K_SEL)     { thrB = tB; doneB = true; }
            else if (cntB > K_SEL) { TB = tB; }
        }
        if (doneA && doneB) break;
    }

    finish_row(A, sA, doneA, thrA, TA, oA, lane);
    finish_row(B, sB, doneB, thrB, TB, oA + D_DIM, lane);
}

extern "C" void kernel_launch(void* const* d_in, const int* in_sizes, int n_in,
                              void* d_out, int out_size, void* d_ws, size_t ws_size,
                              hipStream_t stream) {
    const float* x = (const float*)d_in[0];
    float* out = (float*)d_out;
    const int rows = in_sizes[0] / D_DIM;            // 16384
    sparse_topk_kernel<<<rows / 8, NT, 0, stream>>>(x, out);
}

// Round 7
// 242.916 us; speedup vs baseline: 1.0081x; 1.0081x over previous
//
#include <hip/hip_runtime.h>

// SparseActivation: per row of D=2048 fp32, keep top K=204 by |x|, scale D/K.
// One wave per row-group of 4: persistent wave register-prefetches row r+1's
// 8 float4 while running row r's threshold search (hides HBM latency that
// stalled every short-lived wave in rounds 1-6). Exact Kth-largest via
// seeded integer bisection on abs-bit space: first two probes are constants
// (1.64487, then 1.8/1.5) -- for N(0,1) rows this early-exits (cnt==K,
// provably the exact top-K set) in ~8-10 iterations vs 17 for bit-descent;
// guarded so any data falls back to full correct bisection + exact
// lowest-index-first tie-break.

constexpr int D_DIM = 2048;
constexpr int K_SEL = 204;     // int(2048 * 0.1)
constexpr int NT    = 256;     // 4 waves/block
constexpr int EPL   = 32;      // elements per lane per row
constexpr int RPW   = 4;       // rows per wave

// Full-wave64 integer sum via DPP; returns total (scalar, from lane 63).
__device__ __forceinline__ int dpp_reduce_add(int x) {
    x += __builtin_amdgcn_update_dpp(0, x, 0x111, 0xF, 0xF, true);  // row_shr:1
    x += __builtin_amdgcn_update_dpp(0, x, 0x112, 0xF, 0xF, true);  // row_shr:2
    x += __builtin_amdgcn_update_dpp(0, x, 0x114, 0xF, 0xF, true);  // row_shr:4
    x += __builtin_amdgcn_update_dpp(0, x, 0x118, 0xF, 0xF, true);  // row_shr:8
    x += __builtin_amdgcn_update_dpp(0, x, 0x142, 0xA, 0xF, false); // row_bcast:15
    x += __builtin_amdgcn_update_dpp(0, x, 0x143, 0xC, 0xF, false); // row_bcast:31
    return __builtin_amdgcn_readlane(x, 63);
}

__device__ __forceinline__ int count_ge(const unsigned (&a)[EPL], unsigned t) {
    int c0 = 0, c1 = 0, c2 = 0, c3 = 0;
#pragma unroll
    for (int j = 0; j < EPL; j += 4) {
        c0 += (a[j + 0] >= t) ? 1 : 0;
        c1 += (a[j + 1] >= t) ? 1 : 0;
        c2 += (a[j + 2] >= t) ? 1 : 0;
        c3 += (a[j + 3] >= t) ? 1 : 0;
    }
    return dpp_reduce_add((c0 + c1) + (c2 + c3));
}

// Apply threshold + store one row. exact => thr keep-set has exactly K elems;
// otherwise T is the exact K-th largest and boundary ties are ranked exactly.
__device__ __forceinline__ void finish_row(const unsigned (&a)[EPL], unsigned signs,
                                           bool exact, unsigned thr, unsigned T,
                                           float* __restrict__ outr, int lane) {
    const float scale = 2048.0f / 204.0f;
    float4* op = reinterpret_cast<float4*>(outr);

    if (!exact) {
        // Boundary bookkeeping (gt in low 16 bits, eq in high 16 bits).
        int ge_pack = 0;
#pragma unroll
        for (int j = 0; j < EPL; ++j) {
            ge_pack += (a[j] > T) ? 1 : 0;
            ge_pack += (a[j] == T) ? (1 << 16) : 0;
        }
        const int tot = dpp_reduce_add(ge_pack);
        const int cnt_gt = tot & 0xFFFF;
        const int neq = tot >> 16;
        const int r = K_SEL - cnt_gt;   // equals to keep

        if (neq != r) {
            // Rare: among ==T keep the r with lowest global index.
            const unsigned long long lt =
                (lane == 0) ? 0ull : (~0ull >> (64 - lane));
            int base = 0;
            for (int b = 0; b < 8; ++b) {
                unsigned long long m[4];
#pragma unroll
                for (int e = 0; e < 4; ++e) m[e] = __ballot(a[4 * b + e] == T);
                int cm = 0;
#pragma unroll
                for (int e = 0; e < 4; ++e) cm += __popcll(m[e] & lt);
                int partial = 0;
                float v[4];
#pragma unroll
                for (int e = 0; e < 4; ++e) {
                    const int j = 4 * b + e;
                    const int rank = base + cm + partial;
                    const bool eq = (a[j] == T);
                    const bool sel = (a[j] > T) || (eq && rank < r);
                    const float val =
                        __uint_as_float(a[j] | (((signs >> j) & 1u) << 31)) * scale;
                    v[e] = sel ? val : 0.0f;
                    partial += (int)((m[e] >> lane) & 1ull);
                }
                op[b * 64 + lane] = make_float4(v[0], v[1], v[2], v[3]);
#pragma unroll
                for (int e = 0; e < 4; ++e) base += __popcll(m[e]);
            }
            return;
        }
        thr = T;  // neq == r: keep everything >= T, no tie handling needed
    }

    // Common path: keep everything >= thr; compute+store per 16B chunk.
#pragma unroll
    for (int b = 0; b < 8; ++b) {
        float v[4];
#pragma unroll
        for (int e = 0; e < 4; ++e) {
            const int j = 4 * b + e;
            const float val =
                __uint_as_float(a[j] | (((signs >> j) & 1u) << 31)) * scale;
            v[e] = (a[j] >= thr) ? val : 0.0f;
        }
        op[b * 64 + lane] = make_float4(v[0], v[1], v[2], v[3]);
    }
}

__global__ __launch_bounds__(NT) void sparse_topk_kernel(const float* __restrict__ x,
                                                         float* __restrict__ out) {
    const int wave = threadIdx.x >> 6;
    const int lane = threadIdx.x & 63;
    const long long wid = (long long)blockIdx.x * 4 + wave;
    const float* base = x + wid * RPW * D_DIM;
    float* obase = out + wid * RPW * D_DIM;

    // Prefetch buffer: raw float4s of the row being staged.
    float4 nf[8];
    {
        const float4* p = reinterpret_cast<const float4*>(base);
#pragma unroll
        for (int b = 0; b < 8; ++b) nf[b] = p[b * 64 + lane];
    }

#pragma unroll 1
    for (int r = 0; r < RPW; ++r) {
        // Pack staged row into abs-bits + sign word (this is where the
        // vmcnt wait lands; for r>0 the loads have had a whole search's
        // worth of cycles to complete).
        unsigned a[EPL];
        unsigned signs = 0u;
#pragma unroll
        for (int b = 0; b < 8; ++b) {
            const unsigned w0 = __float_as_uint(nf[b].x);
            const unsigned w1 = __float_as_uint(nf[b].y);
            const unsigned w2 = __float_as_uint(nf[b].z);
            const unsigned w3 = __float_as_uint(nf[b].w);
            a[4 * b + 0] = w0 & 0x7fffffffu; signs |= (w0 >> 31) << (4 * b + 0);
            a[4 * b + 1] = w1 & 0x7fffffffu; signs |= (w1 >> 31) << (4 * b + 1);
            a[4 * b + 2] = w2 & 0x7fffffffu; signs |= (w2 >> 31) << (4 * b + 2);
            a[4 * b + 3] = w3 & 0x7fffffffu; signs |= (w3 >> 31) << (4 * b + 3);
        }

        // Issue next row's loads now; they complete during this row's search.
        if (r + 1 < RPW) {
            const float4* pn = reinterpret_cast<const float4*>(base + (r + 1) * D_DIM);
#pragma unroll
            for (int b = 0; b < 8; ++b) nf[b] = pn[b * 64 + lane];
        }

        // Seeded integer bisection on [lo, hi): invariant cnt_ge(lo) >= K,
        // cnt_ge(hi) < K. Early exit when cnt == K (exact top-K set).
        unsigned lo = 0u, hi = 0x7F800000u;   // cnt_ge(+inf bits) == 0
        unsigned thr = 0u;
        bool exact = false;
        int step = 0, lastcnt = 0;
#pragma unroll 1
        while (hi - lo > 1u) {
            unsigned mid;
            if (step == 0)      mid = 0x3FD28F5Cu;                              // 1.64487
            else if (step == 1) mid = (lastcnt > K_SEL) ? 0x3FE66666u           // 1.8
                                                        : 0x3FC00000u;          // 1.5
            else                mid = lo + ((hi - lo) >> 1);
            if (mid <= lo || mid >= hi) mid = lo + ((hi - lo) >> 1);  // guard seeds
            ++step;
            const int cnt = count_ge(a, mid);
            lastcnt = cnt;
            if (cnt == K_SEL) { thr = mid; exact = true; break; }
            if (cnt > K_SEL) lo = mid; else hi = mid;
        }

        finish_row(a, signs, exact, thr, lo, obase + (long long)r * D_DIM, lane);
    }
}

extern "C" void kernel_launch(void* const* d_in, const int* in_sizes, int n_in,
                              void* d_out, int out_size, void* d_ws, size_t ws_size,
                              hipStream_t stream) {
    const float* x = (const float*)d_in[0];
    float* out = (float*)d_out;
    const int rows = in_sizes[0] / D_DIM;               // 16384
    const int blocks = rows / (RPW * 4);                // 1024
    sparse_topk_kernel<<<blocks, NT, 0, stream>>>(x, out);
}